// Round 2
// baseline (1277.074 us; speedup 1.0000x reference)
//
#include <hip/hip_runtime.h>

// Problem constants (from reference setup_inputs)
#define F_IN 512
#define F1 64          // HEADS*HID = 8*8
#define NCLS 16
#define NEG_SLOPE 0.2f

// ---------------- edge decode (int32 vs int64 robust) ----------------
// Node ids < N=1e5 fit in 32 bits, so an int64 edge array read as int32
// words has ALL odd words == 0. A genuine int32 edge list has random node
// ids at odd positions. 256 samples decides with certainty.

__global__ __launch_bounds__(64) void k_detect(const int* __restrict__ ei, int E,
                                               unsigned* __restrict__ mode) {
    int t = threadIdx.x;
    unsigned nz = 0;
    int lim = (E > 256) ? 256 : E;
    for (int k = t; k < lim; k += 64) nz |= (unsigned)ei[2 * k + 1];
    for (int off = 1; off < 64; off <<= 1) nz |= __shfl_xor(nz, off);
    if (t == 0) *mode = (nz == 0) ? 1u : 0u;   // 1 = int64 layout
}

__global__ __launch_bounds__(256) void k_edges(const int* __restrict__ ei,
                                               const unsigned* __restrict__ mode,
                                               int* __restrict__ src32,
                                               int* __restrict__ dst32,
                                               int N, int E, int ET) {
    int i = blockIdx.x * 256 + threadIdx.x;
    if (i >= ET) return;
    int s, v;
    if (i < E) {
        if (*mode) {
            const long long* e64 = (const long long*)ei;
            s = (int)e64[i];
            v = (int)e64[E + i];
        } else {
            s = ei[i];
            v = ei[E + i];
        }
    } else {
        s = v = i - E;   // self-loops appended
    }
    // safety clamp: a wrong decode must not cause OOB atomics
    s = s < 0 ? 0 : (s >= N ? N - 1 : s);
    v = v < 0 ? 0 : (v >= N ? N - 1 : v);
    src32[i] = s;
    dst32[i] = v;
}

// ---------------- CSR build ----------------

__global__ __launch_bounds__(256) void k_hist(const int* __restrict__ dst,
                                              unsigned* __restrict__ deg, int ET) {
    int i = blockIdx.x * 256 + threadIdx.x;
    if (i >= ET) return;
    atomicAdd(&deg[dst[i]], 1u);
}

__global__ __launch_bounds__(256) void k_tilesum(const unsigned* __restrict__ deg,
                                                 int N, unsigned* __restrict__ tileSum) {
    int tid = threadIdx.x;
    int v = blockIdx.x * 256 + tid;
    unsigned d = (v < N) ? deg[v] : 0u;
    for (int off = 1; off < 64; off <<= 1) d += __shfl_xor(d, off);
    __shared__ unsigned ps[4];
    int lane = tid & 63, wid = tid >> 6;
    if (lane == 0) ps[wid] = d;
    __syncthreads();
    if (tid == 0) tileSum[blockIdx.x] = ps[0] + ps[1] + ps[2] + ps[3];
}

__global__ __launch_bounds__(1024) void k_scan_tiles(const unsigned* __restrict__ tileSum,
                                                     int nt, unsigned* __restrict__ tileOfs) {
    __shared__ unsigned sbuf[1024];
    int t = threadIdx.x;
    unsigned val = (t < nt) ? tileSum[t] : 0u;
    sbuf[t] = val;
    __syncthreads();
    for (int off = 1; off < 1024; off <<= 1) {
        unsigned add = (t >= off) ? sbuf[t - off] : 0u;
        __syncthreads();
        sbuf[t] += add;
        __syncthreads();
    }
    if (t < nt) tileOfs[t] = sbuf[t] - val;  // exclusive
}

__global__ __launch_bounds__(256) void k_rowptr(const unsigned* __restrict__ deg,
                                                const unsigned* __restrict__ tileOfs,
                                                unsigned* __restrict__ row_ptr,
                                                unsigned* __restrict__ fill_ptr,
                                                int N, int ET) {
    __shared__ unsigned sbuf[256];
    int t = threadIdx.x;
    int v = blockIdx.x * 256 + t;
    unsigned d = (v < N) ? deg[v] : 0u;
    sbuf[t] = d;
    __syncthreads();
    for (int off = 1; off < 256; off <<= 1) {
        unsigned add = (t >= off) ? sbuf[t - off] : 0u;
        __syncthreads();
        sbuf[t] += add;
        __syncthreads();
    }
    if (v < N) {
        unsigned excl = tileOfs[blockIdx.x] + sbuf[t] - d;
        row_ptr[v] = excl;
        fill_ptr[v] = excl;
    }
    if (blockIdx.x == 0 && t == 0) row_ptr[N] = (unsigned)ET;
}

__global__ __launch_bounds__(256) void k_scatter(const int* __restrict__ src,
                                                 const int* __restrict__ dst,
                                                 unsigned* __restrict__ fill_ptr,
                                                 unsigned* __restrict__ ssrc, int ET) {
    int i = blockIdx.x * 256 + threadIdx.x;
    if (i >= ET) return;
    unsigned pos = atomicAdd(&fill_ptr[dst[i]], 1u);
    ssrc[pos] = (unsigned)src[i];
}

// ---------------- GEMM1: h1 = x @ W1 (fp32) -> [N,64] ----------------
// 64x64 tile, K-chunks of 64, 256 threads, 4x4 micro-tile per thread.
// LDS rows padded +4 floats: stride 68 mod 32 = 4 -> 2-way bank alias (free).

__global__ __launch_bounds__(256) void k_gemm1(const float* __restrict__ x,
                                               const float* __restrict__ W1,
                                               float* __restrict__ h1, int N) {
    __shared__ float As[64][68];
    __shared__ float Bs[64][68];
    int tid = threadIdx.x;
    int row0 = blockIdx.x * 64;
    int tc = tid & 15;       // col quad
    int tr = tid >> 4;       // row quad
    int lrow = tid >> 2;     // 0..63 staging row
    int lseg = (tid & 3) * 16;

    float acc[4][4];
#pragma unroll
    for (int i = 0; i < 4; i++)
#pragma unroll
        for (int j = 0; j < 4; j++) acc[i][j] = 0.f;

    int ar = row0 + lrow;
    for (int k0 = 0; k0 < F_IN; k0 += 64) {
#pragma unroll
        for (int q = 0; q < 4; q++) {
            float4 av = make_float4(0.f, 0.f, 0.f, 0.f);
            if (ar < N) av = *(const float4*)(x + (size_t)ar * F_IN + k0 + lseg + q * 4);
            *(float4*)&As[lrow][lseg + q * 4] = av;
            float4 bv = *(const float4*)(W1 + (size_t)(k0 + lrow) * F1 + lseg + q * 4);
            *(float4*)&Bs[lrow][lseg + q * 4] = bv;
        }
        __syncthreads();

#pragma unroll
        for (int kk = 0; kk < 64; kk += 4) {
            float a[4][4], b[4][4];
#pragma unroll
            for (int i = 0; i < 4; i++)
                *(float4*)&a[i][0] = *(const float4*)&As[tr * 4 + i][kk];
#pragma unroll
            for (int kx = 0; kx < 4; kx++)
                *(float4*)&b[kx][0] = *(const float4*)&Bs[kk + kx][tc * 4];
#pragma unroll
            for (int kx = 0; kx < 4; kx++)
#pragma unroll
                for (int i = 0; i < 4; i++)
#pragma unroll
                    for (int j = 0; j < 4; j++)
                        acc[i][j] = fmaf(a[i][kx], b[kx][j], acc[i][j]);
        }
        __syncthreads();
    }

#pragma unroll
    for (int i = 0; i < 4; i++) {
        int r = row0 + tr * 4 + i;
        if (r < N) {
            float4 o = make_float4(acc[i][0], acc[i][1], acc[i][2], acc[i][3]);
            *(float4*)(h1 + (size_t)r * F1 + tc * 4) = o;
        }
    }
}

// ---------------- attention dots layer 1: a_s/a_d [N,8] ----------------

__global__ __launch_bounds__(256) void k_attdots1(const float* __restrict__ h1,
                                                  const float* __restrict__ att_src,
                                                  const float* __restrict__ att_dst,
                                                  float* __restrict__ a_s,
                                                  float* __restrict__ a_d, int N) {
    int gidx = blockIdx.x * 256 + threadIdx.x;
    int n = gidx >> 6;
    int c = gidx & 63;
    float v = (n < N) ? h1[gidx] : 0.f;
    float s = v * att_src[c];
    float d = v * att_dst[c];
    s += __shfl_xor(s, 1); s += __shfl_xor(s, 2); s += __shfl_xor(s, 4);
    d += __shfl_xor(d, 1); d += __shfl_xor(d, 2); d += __shfl_xor(d, 4);
    if (n < N && (c & 7) == 0) {
        a_s[n * 8 + (c >> 3)] = s;
        a_d[n * 8 + (c >> 3)] = d;
    }
}

// ---------------- layer-1 aggregation: one wave per dst node ----------------

__global__ __launch_bounds__(256) void k_agg1(const float* __restrict__ h1,
                                              const float* __restrict__ a_s1,
                                              const float* __restrict__ a_d1,
                                              const float* __restrict__ b1,
                                              const unsigned* __restrict__ row_ptr,
                                              const unsigned* __restrict__ ssrc,
                                              float* __restrict__ g, int N) {
    int wid = threadIdx.x >> 6, lane = threadIdx.x & 63;
    int v = blockIdx.x * 4 + wid;
    if (v >= N) return;
    unsigned base = row_ptr[v];
    unsigned deg = row_ptr[v + 1] - base;

    float adv[8];
#pragma unroll
    for (int h = 0; h < 8; h++) adv[h] = a_d1[(size_t)v * 8 + h];

    float m[8];
#pragma unroll
    for (int h = 0; h < 8; h++) m[h] = -1e30f;

    // phase A: per-head max over incoming edges
    for (unsigned j = lane; j < deg; j += 64) {
        unsigned s = ssrc[base + j];
        const float4* ap = (const float4*)(a_s1 + (size_t)s * 8);
        float4 p0 = ap[0], p1 = ap[1];
        float e;
        e = p0.x + adv[0]; e = e > 0.f ? e : NEG_SLOPE * e; m[0] = fmaxf(m[0], e);
        e = p0.y + adv[1]; e = e > 0.f ? e : NEG_SLOPE * e; m[1] = fmaxf(m[1], e);
        e = p0.z + adv[2]; e = e > 0.f ? e : NEG_SLOPE * e; m[2] = fmaxf(m[2], e);
        e = p0.w + adv[3]; e = e > 0.f ? e : NEG_SLOPE * e; m[3] = fmaxf(m[3], e);
        e = p1.x + adv[4]; e = e > 0.f ? e : NEG_SLOPE * e; m[4] = fmaxf(m[4], e);
        e = p1.y + adv[5]; e = e > 0.f ? e : NEG_SLOPE * e; m[5] = fmaxf(m[5], e);
        e = p1.z + adv[6]; e = e > 0.f ? e : NEG_SLOPE * e; m[6] = fmaxf(m[6], e);
        e = p1.w + adv[7]; e = e > 0.f ? e : NEG_SLOPE * e; m[7] = fmaxf(m[7], e);
    }
#pragma unroll
    for (int h = 0; h < 8; h++)
        for (int off = 32; off >= 1; off >>= 1)
            m[h] = fmaxf(m[h], __shfl_xor(m[h], off));

    // phase B: sum of exp(e - max)
    float sm[8];
#pragma unroll
    for (int h = 0; h < 8; h++) sm[h] = 0.f;
    for (unsigned j = lane; j < deg; j += 64) {
        unsigned s = ssrc[base + j];
        const float4* ap = (const float4*)(a_s1 + (size_t)s * 8);
        float4 p0 = ap[0], p1 = ap[1];
        float e;
        e = p0.x + adv[0]; e = e > 0.f ? e : NEG_SLOPE * e; sm[0] += __expf(e - m[0]);
        e = p0.y + adv[1]; e = e > 0.f ? e : NEG_SLOPE * e; sm[1] += __expf(e - m[1]);
        e = p0.z + adv[2]; e = e > 0.f ? e : NEG_SLOPE * e; sm[2] += __expf(e - m[2]);
        e = p0.w + adv[3]; e = e > 0.f ? e : NEG_SLOPE * e; sm[3] += __expf(e - m[3]);
        e = p1.x + adv[4]; e = e > 0.f ? e : NEG_SLOPE * e; sm[4] += __expf(e - m[4]);
        e = p1.y + adv[5]; e = e > 0.f ? e : NEG_SLOPE * e; sm[5] += __expf(e - m[5]);
        e = p1.z + adv[6]; e = e > 0.f ? e : NEG_SLOPE * e; sm[6] += __expf(e - m[6]);
        e = p1.w + adv[7]; e = e > 0.f ? e : NEG_SLOPE * e; sm[7] += __expf(e - m[7]);
    }
#pragma unroll
    for (int h = 0; h < 8; h++)
        for (int off = 32; off >= 1; off >>= 1)
            sm[h] += __shfl_xor(sm[h], off);

    // per-lane (h,c): lane = h*8+c
    int h = lane >> 3;
    float mh = m[0], dh = sm[0], ah = adv[0];
#pragma unroll
    for (int q = 1; q < 8; q++) {
        if (h == q) { mh = m[q]; dh = sm[q]; ah = adv[q]; }
    }
    float rdh = 1.0f / dh;

    // phase C: weighted aggregation, channel-parallel
    float acc = 0.f;
    for (unsigned j = 0; j < deg; j++) {
        unsigned s = ssrc[base + j];
        float e = a_s1[(size_t)s * 8 + h] + ah;
        e = e > 0.f ? e : NEG_SLOPE * e;
        float alpha = __expf(e - mh) * rdh;
        acc = fmaf(h1[(size_t)s * F1 + lane], alpha, acc);
    }
    float t = acc + b1[lane];
    g[(size_t)v * F1 + lane] = t > 0.f ? t : (__expf(t) - 1.f);  // ELU
}

// ---------------- GEMM2 + attention dots layer 2 ----------------

__global__ __launch_bounds__(256) void k_gemm2(const float* __restrict__ g,
                                               const float* __restrict__ W2,
                                               const float* __restrict__ as2w,
                                               const float* __restrict__ ad2w,
                                               float* __restrict__ h2,
                                               float* __restrict__ a_s2,
                                               float* __restrict__ a_d2, int N) {
    __shared__ float W2s[F1][NCLS];
    int tid = threadIdx.x;
    for (int i = tid; i < F1 * NCLS; i += 256) ((float*)W2s)[i] = W2[i];
    __syncthreads();
    int lane = tid & 63, wid = tid >> 6;
    int n = blockIdx.x * 16 + wid * 4 + (lane >> 4);
    int c = lane & 15;
    if (n >= N) return;
    float acc = 0.f;
#pragma unroll
    for (int k4 = 0; k4 < 16; k4++) {
        float4 gv = *(const float4*)(g + (size_t)n * F1 + k4 * 4);
        acc = fmaf(gv.x, W2s[k4 * 4 + 0][c], acc);
        acc = fmaf(gv.y, W2s[k4 * 4 + 1][c], acc);
        acc = fmaf(gv.z, W2s[k4 * 4 + 2][c], acc);
        acc = fmaf(gv.w, W2s[k4 * 4 + 3][c], acc);
    }
    h2[(size_t)n * NCLS + c] = acc;
    float s = acc * as2w[c];
    float d = acc * ad2w[c];
    s += __shfl_xor(s, 1); s += __shfl_xor(s, 2); s += __shfl_xor(s, 4); s += __shfl_xor(s, 8);
    d += __shfl_xor(d, 1); d += __shfl_xor(d, 2); d += __shfl_xor(d, 4); d += __shfl_xor(d, 8);
    if (c == 0) { a_s2[n] = s; a_d2[n] = d; }
}

// ---------------- layer-2 aggregation -> fp32 output ----------------

__global__ __launch_bounds__(256) void k_agg2(const float* __restrict__ h2,
                                              const float* __restrict__ a_s2,
                                              const float* __restrict__ a_d2,
                                              const float* __restrict__ b2,
                                              const unsigned* __restrict__ row_ptr,
                                              const unsigned* __restrict__ ssrc,
                                              float* __restrict__ out, int N) {
    int wid = threadIdx.x >> 6, lane = threadIdx.x & 63;
    int v = blockIdx.x * 4 + wid;
    if (v >= N) return;
    unsigned base = row_ptr[v];
    unsigned deg = row_ptr[v + 1] - base;
    float adv = a_d2[v];

    float m = -1e30f;
    for (unsigned j = lane; j < deg; j += 64) {
        unsigned s = ssrc[base + j];
        float e = a_s2[s] + adv;
        e = e > 0.f ? e : NEG_SLOPE * e;
        m = fmaxf(m, e);
    }
    for (int off = 32; off >= 1; off >>= 1) m = fmaxf(m, __shfl_xor(m, off));

    float sm = 0.f;
    for (unsigned j = lane; j < deg; j += 64) {
        unsigned s = ssrc[base + j];
        float e = a_s2[s] + adv;
        e = e > 0.f ? e : NEG_SLOPE * e;
        sm += __expf(e - m);
    }
    for (int off = 32; off >= 1; off >>= 1) sm += __shfl_xor(sm, off);
    float rs = 1.0f / sm;

    int sub = lane >> 4, c = lane & 15;
    float acc = 0.f;
    for (unsigned j0 = 0; j0 < deg; j0 += 4) {
        unsigned j = j0 + sub;
        if (j < deg) {
            unsigned s = ssrc[base + j];
            float e = a_s2[s] + adv;
            e = e > 0.f ? e : NEG_SLOPE * e;
            float alpha = __expf(e - m) * rs;
            acc = fmaf(h2[(size_t)s * NCLS + c], alpha, acc);
        }
    }
    acc += __shfl_xor(acc, 16);
    acc += __shfl_xor(acc, 32);
    if (lane < 16) {
        out[(size_t)v * NCLS + c] = acc + b2[c];
    }
}

// ---------------- launch ----------------

static inline size_t algn(size_t x) { return (x + 255) & ~(size_t)255; }

extern "C" void kernel_launch(void* const* d_in, const int* in_sizes, int n_in,
                              void* d_out, int out_size, void* d_ws, size_t ws_size,
                              hipStream_t stream) {
    const float* x   = (const float*)d_in[0];
    const int* ei    = (const int*)d_in[1];
    const float* W1  = (const float*)d_in[2];
    const float* as1 = (const float*)d_in[3];
    const float* ad1 = (const float*)d_in[4];
    const float* b1  = (const float*)d_in[5];
    const float* W2  = (const float*)d_in[6];
    const float* as2 = (const float*)d_in[7];
    const float* ad2 = (const float*)d_in[8];
    const float* b2  = (const float*)d_in[9];

    const int N = in_sizes[0] / F_IN;
    const int E = in_sizes[1] / 2;
    const int ET = E + N;
    const int nt = (N + 255) / 256;   // scan tiles (<= 1024)

    char* p = (char*)d_ws;
    float* h1   = (float*)p;      p += algn((size_t)N * F1 * 4);
    float* g    = (float*)p;      p += algn((size_t)N * F1 * 4);
    float* a_s1 = (float*)p;      p += algn((size_t)N * 8 * 4);
    float* a_d1 = (float*)p;      p += algn((size_t)N * 8 * 4);
    float* h2   = (float*)p;      p += algn((size_t)N * NCLS * 4);
    float* a_s2 = (float*)p;      p += algn((size_t)N * 4);
    float* a_d2 = (float*)p;      p += algn((size_t)N * 4);
    unsigned* deg     = (unsigned*)p;  p += algn((size_t)N * 4);
    unsigned* fill    = (unsigned*)p;  p += algn((size_t)N * 4);
    unsigned* row_ptr = (unsigned*)p;  p += algn((size_t)(N + 1) * 4);
    unsigned* tileSum = (unsigned*)p;  p += algn((size_t)1024 * 4);
    unsigned* tileOfs = (unsigned*)p;  p += algn((size_t)1024 * 4);
    unsigned* mode    = (unsigned*)p;  p += algn(256);
    int* src32 = (int*)p;              p += algn((size_t)ET * 4);
    int* dst32 = (int*)p;              p += algn((size_t)ET * 4);
    unsigned* ssrc = (unsigned*)p;     p += algn((size_t)ET * 4);

    hipMemsetAsync(deg, 0, (size_t)N * 4, stream);

    dim3 b256(256);
    k_detect<<<dim3(1), dim3(64), 0, stream>>>(ei, E, mode);
    k_edges<<<dim3((ET + 255) / 256), b256, 0, stream>>>(ei, mode, src32, dst32, N, E, ET);
    k_hist<<<dim3((ET + 255) / 256), b256, 0, stream>>>(dst32, deg, ET);
    k_tilesum<<<dim3(nt), b256, 0, stream>>>(deg, N, tileSum);
    k_scan_tiles<<<dim3(1), dim3(1024), 0, stream>>>(tileSum, nt, tileOfs);
    k_rowptr<<<dim3(nt), b256, 0, stream>>>(deg, tileOfs, row_ptr, fill, N, ET);
    k_scatter<<<dim3((ET + 255) / 256), b256, 0, stream>>>(src32, dst32, fill, ssrc, ET);

    k_gemm1<<<dim3((N + 63) / 64), b256, 0, stream>>>(x, W1, h1, N);
    k_attdots1<<<dim3((N * F1 + 255) / 256), b256, 0, stream>>>(h1, as1, ad1, a_s1, a_d1, N);
    k_agg1<<<dim3((N + 3) / 4), b256, 0, stream>>>(h1, a_s1, a_d1, b1, row_ptr, ssrc, g, N);
    k_gemm2<<<dim3((N + 15) / 16), b256, 0, stream>>>(g, W2, as2, ad2, h2, a_s2, a_d2, N);
    k_agg2<<<dim3((N + 3) / 4), b256, 0, stream>>>(h2, a_s2, a_d2, b2, row_ptr, ssrc,
                                                   (float*)d_out, N);
}

// Round 3
// 1029.655 us; speedup vs baseline: 1.2403x; 1.2403x over previous
//
#include <hip/hip_runtime.h>

// Problem constants (from reference setup_inputs)
#define F_IN 512
#define F1 64          // HEADS*HID = 8*8
#define NCLS 16
#define NEG_SLOPE 0.2f

// ---------------- edge decode (int32 vs int64 robust) + degree hist ----------
// Node ids < N=1e5 fit in 32 bits, so an int64 edge array read as int32
// words has ALL odd words == 0. 256 samples decides with certainty.

__global__ __launch_bounds__(64) void k_detect(const int* __restrict__ ei, int E,
                                               unsigned* __restrict__ mode) {
    int t = threadIdx.x;
    unsigned nz = 0;
    int lim = (E > 256) ? 256 : E;
    for (int k = t; k < lim; k += 64) nz |= (unsigned)ei[2 * k + 1];
    for (int off = 1; off < 64; off <<= 1) nz |= __shfl_xor(nz, off);
    if (t == 0) *mode = (nz == 0) ? 1u : 0u;   // 1 = int64 layout
}

__global__ __launch_bounds__(256) void k_edges(const int* __restrict__ ei,
                                               const unsigned* __restrict__ mode,
                                               int* __restrict__ src32,
                                               int* __restrict__ dst32,
                                               unsigned* __restrict__ deg,
                                               int N, int E, int ET) {
    int i = blockIdx.x * 256 + threadIdx.x;
    if (i >= ET) return;
    int s, v;
    if (i < E) {
        if (*mode) {
            const long long* e64 = (const long long*)ei;
            s = (int)e64[i];
            v = (int)e64[E + i];
        } else {
            s = ei[i];
            v = ei[E + i];
        }
    } else {
        s = v = i - E;   // self-loops appended
    }
    s = s < 0 ? 0 : (s >= N ? N - 1 : s);
    v = v < 0 ? 0 : (v >= N ? N - 1 : v);
    src32[i] = s;
    dst32[i] = v;
    atomicAdd(&deg[v], 1u);
}

// ---------------- CSR build ----------------

__global__ __launch_bounds__(256) void k_tilesum(const unsigned* __restrict__ deg,
                                                 int N, unsigned* __restrict__ tileSum) {
    int tid = threadIdx.x;
    int v = blockIdx.x * 256 + tid;
    unsigned d = (v < N) ? deg[v] : 0u;
    for (int off = 1; off < 64; off <<= 1) d += __shfl_xor(d, off);
    __shared__ unsigned ps[4];
    int lane = tid & 63, wid = tid >> 6;
    if (lane == 0) ps[wid] = d;
    __syncthreads();
    if (tid == 0) tileSum[blockIdx.x] = ps[0] + ps[1] + ps[2] + ps[3];
}

__global__ __launch_bounds__(1024) void k_scan_tiles(const unsigned* __restrict__ tileSum,
                                                     int nt, unsigned* __restrict__ tileOfs) {
    __shared__ unsigned sbuf[1024];
    int t = threadIdx.x;
    unsigned val = (t < nt) ? tileSum[t] : 0u;
    sbuf[t] = val;
    __syncthreads();
    for (int off = 1; off < 1024; off <<= 1) {
        unsigned add = (t >= off) ? sbuf[t - off] : 0u;
        __syncthreads();
        sbuf[t] += add;
        __syncthreads();
    }
    if (t < nt) tileOfs[t] = sbuf[t] - val;  // exclusive
}

__global__ __launch_bounds__(256) void k_rowptr(const unsigned* __restrict__ deg,
                                                const unsigned* __restrict__ tileOfs,
                                                unsigned* __restrict__ row_ptr,
                                                unsigned* __restrict__ fill_ptr,
                                                int N, int ET) {
    __shared__ unsigned sbuf[256];
    int t = threadIdx.x;
    int v = blockIdx.x * 256 + t;
    unsigned d = (v < N) ? deg[v] : 0u;
    sbuf[t] = d;
    __syncthreads();
    for (int off = 1; off < 256; off <<= 1) {
        unsigned add = (t >= off) ? sbuf[t - off] : 0u;
        __syncthreads();
        sbuf[t] += add;
        __syncthreads();
    }
    if (v < N) {
        unsigned excl = tileOfs[blockIdx.x] + sbuf[t] - d;
        row_ptr[v] = excl;
        fill_ptr[v] = excl;
    }
    if (blockIdx.x == 0 && t == 0) row_ptr[N] = (unsigned)ET;
}

__global__ __launch_bounds__(256) void k_scatter(const int* __restrict__ src,
                                                 const int* __restrict__ dst,
                                                 unsigned* __restrict__ fill_ptr,
                                                 unsigned* __restrict__ ssrc, int ET) {
    int i = blockIdx.x * 256 + threadIdx.x;
    if (i >= ET) return;
    unsigned pos = atomicAdd(&fill_ptr[dst[i]], 1u);
    ssrc[pos] = (unsigned)src[i];
}

// ---------------- GEMM1: h1 = x @ W1 (fp32) -> [N,64] + fused att-dots ------
// 64x64 tile, K-chunks of 64, 256 threads, 4x4 micro-tile per thread.
// LDS rows padded +4 floats (stride 68 mod 32 = 4 -> 2-way alias, free).
// Epilogue: a_s1[n,h] = sum_c h[n,h*8+c]*att_s[h*8+c] via in-thread 4-dot
// + one xor-1 shuffle (each thread holds 4 cols of one head-half).

__global__ __launch_bounds__(256) void k_gemm1(const float* __restrict__ x,
                                               const float* __restrict__ W1,
                                               const float* __restrict__ att_s,
                                               const float* __restrict__ att_d,
                                               float* __restrict__ h1,
                                               float* __restrict__ a_s1,
                                               float* __restrict__ a_d1, int N) {
    __shared__ float As[64][68];
    __shared__ float Bs[64][68];
    int tid = threadIdx.x;
    int row0 = blockIdx.x * 64;
    int tc = tid & 15;       // col quad
    int tr = tid >> 4;       // row quad
    int lrow = tid >> 2;     // 0..63 staging row
    int lseg = (tid & 3) * 16;

    float acc[4][4];
#pragma unroll
    for (int i = 0; i < 4; i++)
#pragma unroll
        for (int j = 0; j < 4; j++) acc[i][j] = 0.f;

    int ar = row0 + lrow;
    for (int k0 = 0; k0 < F_IN; k0 += 64) {
#pragma unroll
        for (int q = 0; q < 4; q++) {
            float4 av = make_float4(0.f, 0.f, 0.f, 0.f);
            if (ar < N) av = *(const float4*)(x + (size_t)ar * F_IN + k0 + lseg + q * 4);
            *(float4*)&As[lrow][lseg + q * 4] = av;
            float4 bv = *(const float4*)(W1 + (size_t)(k0 + lrow) * F1 + lseg + q * 4);
            *(float4*)&Bs[lrow][lseg + q * 4] = bv;
        }
        __syncthreads();

#pragma unroll
        for (int kk = 0; kk < 64; kk += 4) {
            float a[4][4], b[4][4];
#pragma unroll
            for (int i = 0; i < 4; i++)
                *(float4*)&a[i][0] = *(const float4*)&As[tr * 4 + i][kk];
#pragma unroll
            for (int kx = 0; kx < 4; kx++)
                *(float4*)&b[kx][0] = *(const float4*)&Bs[kk + kx][tc * 4];
#pragma unroll
            for (int kx = 0; kx < 4; kx++)
#pragma unroll
                for (int i = 0; i < 4; i++)
#pragma unroll
                    for (int j = 0; j < 4; j++)
                        acc[i][j] = fmaf(a[i][kx], b[kx][j], acc[i][j]);
        }
        __syncthreads();
    }

    float4 ats = *(const float4*)(att_s + tc * 4);
    float4 atd = *(const float4*)(att_d + tc * 4);
#pragma unroll
    for (int i = 0; i < 4; i++) {
        int r = row0 + tr * 4 + i;
        if (r < N) {
            float4 o = make_float4(acc[i][0], acc[i][1], acc[i][2], acc[i][3]);
            *(float4*)(h1 + (size_t)r * F1 + tc * 4) = o;
        }
        float ps = acc[i][0] * ats.x + acc[i][1] * ats.y + acc[i][2] * ats.z + acc[i][3] * ats.w;
        float pd = acc[i][0] * atd.x + acc[i][1] * atd.y + acc[i][2] * atd.z + acc[i][3] * atd.w;
        ps += __shfl_xor(ps, 1);
        pd += __shfl_xor(pd, 1);
        if (r < N && (tc & 1) == 0) {
            a_s1[(size_t)r * 8 + (tc >> 1)] = ps;
            a_d1[(size_t)r * 8 + (tc >> 1)] = pd;
        }
    }
}

// ---------------- layer-1 aggregation: one wave per dst node ----------------
// Single-pass softmax: out = sum(exp(e)*h1[s]) / sum(exp(e)).
// lane = head*8 + channel; each lane accumulates its head's denom privately.
// 4-deep unroll for memory-level parallelism.

__global__ __launch_bounds__(256) void k_agg1(const float* __restrict__ h1,
                                              const float* __restrict__ a_s1,
                                              const float* __restrict__ a_d1,
                                              const float* __restrict__ b1,
                                              const unsigned* __restrict__ row_ptr,
                                              const unsigned* __restrict__ ssrc,
                                              float* __restrict__ g, int N) {
    int wid = threadIdx.x >> 6, lane = threadIdx.x & 63;
    int v = blockIdx.x * 4 + wid;
    if (v >= N) return;
    unsigned base = row_ptr[v];
    unsigned deg = row_ptr[v + 1] - base;
    int h = lane >> 3;
    float adv = a_d1[(size_t)v * 8 + h];

    float denom = 0.f, acc = 0.f;
    unsigned j = 0;
    for (; j + 4 <= deg; j += 4) {
        unsigned s0 = ssrc[base + j + 0];
        unsigned s1 = ssrc[base + j + 1];
        unsigned s2 = ssrc[base + j + 2];
        unsigned s3 = ssrc[base + j + 3];
        float as0 = a_s1[(size_t)s0 * 8 + h];
        float as1 = a_s1[(size_t)s1 * 8 + h];
        float as2 = a_s1[(size_t)s2 * 8 + h];
        float as3 = a_s1[(size_t)s3 * 8 + h];
        float h0 = h1[(size_t)s0 * F1 + lane];
        float hv1 = h1[(size_t)s1 * F1 + lane];
        float hv2 = h1[(size_t)s2 * F1 + lane];
        float hv3 = h1[(size_t)s3 * F1 + lane];
        float e0 = as0 + adv; e0 = e0 > 0.f ? e0 : NEG_SLOPE * e0; float p0 = __expf(e0);
        float e1 = as1 + adv; e1 = e1 > 0.f ? e1 : NEG_SLOPE * e1; float p1 = __expf(e1);
        float e2 = as2 + adv; e2 = e2 > 0.f ? e2 : NEG_SLOPE * e2; float p2 = __expf(e2);
        float e3 = as3 + adv; e3 = e3 > 0.f ? e3 : NEG_SLOPE * e3; float p3 = __expf(e3);
        denom += (p0 + p1) + (p2 + p3);
        acc = fmaf(h0, p0, acc);
        acc = fmaf(hv1, p1, acc);
        acc = fmaf(hv2, p2, acc);
        acc = fmaf(hv3, p3, acc);
    }
    for (; j < deg; j++) {
        unsigned s = ssrc[base + j];
        float as = a_s1[(size_t)s * 8 + h];
        float hv = h1[(size_t)s * F1 + lane];
        float e = as + adv; e = e > 0.f ? e : NEG_SLOPE * e;
        float p = __expf(e);
        denom += p;
        acc = fmaf(hv, p, acc);
    }
    float t = acc * (1.0f / denom) + b1[lane];
    g[(size_t)v * F1 + lane] = t > 0.f ? t : (__expf(t) - 1.f);  // ELU
}

// ---------------- GEMM2 + attention dots layer 2 ----------------

__global__ __launch_bounds__(256) void k_gemm2(const float* __restrict__ g,
                                               const float* __restrict__ W2,
                                               const float* __restrict__ as2w,
                                               const float* __restrict__ ad2w,
                                               float* __restrict__ h2,
                                               float* __restrict__ a_s2,
                                               float* __restrict__ a_d2, int N) {
    __shared__ float W2s[F1][NCLS];
    int tid = threadIdx.x;
    for (int i = tid; i < F1 * NCLS; i += 256) ((float*)W2s)[i] = W2[i];
    __syncthreads();
    int lane = tid & 63, wid = tid >> 6;
    int n = blockIdx.x * 16 + wid * 4 + (lane >> 4);
    int c = lane & 15;
    if (n >= N) return;
    float acc = 0.f;
#pragma unroll
    for (int k4 = 0; k4 < 16; k4++) {
        float4 gv = *(const float4*)(g + (size_t)n * F1 + k4 * 4);
        acc = fmaf(gv.x, W2s[k4 * 4 + 0][c], acc);
        acc = fmaf(gv.y, W2s[k4 * 4 + 1][c], acc);
        acc = fmaf(gv.z, W2s[k4 * 4 + 2][c], acc);
        acc = fmaf(gv.w, W2s[k4 * 4 + 3][c], acc);
    }
    h2[(size_t)n * NCLS + c] = acc;
    float s = acc * as2w[c];
    float d = acc * ad2w[c];
    s += __shfl_xor(s, 1); s += __shfl_xor(s, 2); s += __shfl_xor(s, 4); s += __shfl_xor(s, 8);
    d += __shfl_xor(d, 1); d += __shfl_xor(d, 2); d += __shfl_xor(d, 4); d += __shfl_xor(d, 8);
    if (c == 0) { a_s2[n] = s; a_d2[n] = d; }
}

// ---------------- layer-2 aggregation (single-pass) -> fp32 output ----------
// lanes: 4 subgroups x 16 channels; subgroup handles edges j = sub (mod 4).
// Per-lane partial denom/acc, xor-16/32 reduce at the end.

__global__ __launch_bounds__(256) void k_agg2(const float* __restrict__ h2,
                                              const float* __restrict__ a_s2,
                                              const float* __restrict__ a_d2,
                                              const float* __restrict__ b2,
                                              const unsigned* __restrict__ row_ptr,
                                              const unsigned* __restrict__ ssrc,
                                              float* __restrict__ out, int N) {
    int wid = threadIdx.x >> 6, lane = threadIdx.x & 63;
    int v = blockIdx.x * 4 + wid;
    if (v >= N) return;
    unsigned base = row_ptr[v];
    unsigned deg = row_ptr[v + 1] - base;
    float adv = a_d2[v];
    int sub = lane >> 4, c = lane & 15;

    float denom = 0.f, acc = 0.f;
    for (unsigned j = sub; j < deg; j += 4) {
        unsigned s = ssrc[base + j];
        float as = a_s2[s];
        float hv = h2[(size_t)s * NCLS + c];
        float e = as + adv; e = e > 0.f ? e : NEG_SLOPE * e;
        float p = __expf(e);
        denom += p;
        acc = fmaf(hv, p, acc);
    }
    acc += __shfl_xor(acc, 16);
    acc += __shfl_xor(acc, 32);
    denom += __shfl_xor(denom, 16);
    denom += __shfl_xor(denom, 32);
    if (lane < 16) {
        out[(size_t)v * NCLS + c] = acc * (1.0f / denom) + b2[c];
    }
}

// ---------------- launch ----------------

static inline size_t algn(size_t x) { return (x + 255) & ~(size_t)255; }

extern "C" void kernel_launch(void* const* d_in, const int* in_sizes, int n_in,
                              void* d_out, int out_size, void* d_ws, size_t ws_size,
                              hipStream_t stream) {
    const float* x   = (const float*)d_in[0];
    const int* ei    = (const int*)d_in[1];
    const float* W1  = (const float*)d_in[2];
    const float* as1 = (const float*)d_in[3];
    const float* ad1 = (const float*)d_in[4];
    const float* b1  = (const float*)d_in[5];
    const float* W2  = (const float*)d_in[6];
    const float* as2 = (const float*)d_in[7];
    const float* ad2 = (const float*)d_in[8];
    const float* b2  = (const float*)d_in[9];

    const int N = in_sizes[0] / F_IN;
    const int E = in_sizes[1] / 2;
    const int ET = E + N;
    const int nt = (N + 255) / 256;   // scan tiles (<= 1024)

    char* p = (char*)d_ws;
    float* h1   = (float*)p;      p += algn((size_t)N * F1 * 4);
    float* g    = (float*)p;      p += algn((size_t)N * F1 * 4);
    float* a_s1 = (float*)p;      p += algn((size_t)N * 8 * 4);
    float* a_d1 = (float*)p;      p += algn((size_t)N * 8 * 4);
    float* h2   = (float*)p;      p += algn((size_t)N * NCLS * 4);
    float* a_s2 = (float*)p;      p += algn((size_t)N * 4);
    float* a_d2 = (float*)p;      p += algn((size_t)N * 4);
    unsigned* deg     = (unsigned*)p;  p += algn((size_t)N * 4);
    unsigned* fill    = (unsigned*)p;  p += algn((size_t)N * 4);
    unsigned* row_ptr = (unsigned*)p;  p += algn((size_t)(N + 1) * 4);
    unsigned* tileSum = (unsigned*)p;  p += algn((size_t)1024 * 4);
    unsigned* tileOfs = (unsigned*)p;  p += algn((size_t)1024 * 4);
    unsigned* mode    = (unsigned*)p;  p += algn(256);
    int* src32 = (int*)p;              p += algn((size_t)ET * 4);
    int* dst32 = (int*)p;              p += algn((size_t)ET * 4);
    unsigned* ssrc = (unsigned*)p;     p += algn((size_t)ET * 4);

    hipMemsetAsync(deg, 0, (size_t)N * 4, stream);

    dim3 b256(256);
    k_detect<<<dim3(1), dim3(64), 0, stream>>>(ei, E, mode);
    k_edges<<<dim3((ET + 255) / 256), b256, 0, stream>>>(ei, mode, src32, dst32, deg, N, E, ET);
    k_tilesum<<<dim3(nt), b256, 0, stream>>>(deg, N, tileSum);
    k_scan_tiles<<<dim3(1), dim3(1024), 0, stream>>>(tileSum, nt, tileOfs);
    k_rowptr<<<dim3(nt), b256, 0, stream>>>(deg, tileOfs, row_ptr, fill, N, ET);
    k_scatter<<<dim3((ET + 255) / 256), b256, 0, stream>>>(src32, dst32, fill, ssrc, ET);

    k_gemm1<<<dim3((N + 63) / 64), b256, 0, stream>>>(x, W1, as1, ad1, h1, a_s1, a_d1, N);
    k_agg1<<<dim3((N + 3) / 4), b256, 0, stream>>>(h1, a_s1, a_d1, b1, row_ptr, ssrc, g, N);
    k_gemm2<<<dim3((N + 15) / 16), b256, 0, stream>>>(g, W2, as2, ad2, h2, a_s2, a_d2, N);
    k_agg2<<<dim3((N + 3) / 4), b256, 0, stream>>>(h2, a_s2, a_d2, b2, row_ptr, ssrc,
                                                   (float*)d_out, N);
}

// Round 4
// 805.655 us; speedup vs baseline: 1.5851x; 1.2780x over previous
//
#include <hip/hip_runtime.h>

// Problem constants (from reference setup_inputs)
#define F_IN 512
#define F1 64          // HEADS*HID = 8*8
#define NCLS 16
#define NEG_SLOPE 0.2f

// ---------------- edge decode (int32 vs int64 robust) ----------------

__global__ __launch_bounds__(64) void k_detect(const int* __restrict__ ei, int E,
                                               unsigned* __restrict__ mode) {
    int t = threadIdx.x;
    unsigned nz = 0;
    int lim = (E > 256) ? 256 : E;
    for (int k = t; k < lim; k += 64) nz |= (unsigned)ei[2 * k + 1];
    for (int off = 1; off < 64; off <<= 1) nz |= __shfl_xor(nz, off);
    if (t == 0) *mode = (nz == 0) ? 1u : 0u;   // 1 = int64 layout
}

// ---------------- GEMM1 tile as device function ----------------
// 64x64 tile, K-chunks of 64, 256 threads, 4x4 micro-tile per thread.
// LDS rows padded +4 (stride 68 mod 32 = 4 -> 2-way alias, free).
// Fused epilogue: per-head attention dots via in-thread 4-dot + xor-1 shuffle.

__device__ __forceinline__ void gemm1_tile(const float* __restrict__ x,
                                           const float* __restrict__ W1,
                                           const float* __restrict__ att_s,
                                           const float* __restrict__ att_d,
                                           float* __restrict__ h1,
                                           float* __restrict__ a_s1,
                                           float* __restrict__ a_d1,
                                           int N, int row0,
                                           float (*As)[68], float (*Bs)[68]) {
    int tid = threadIdx.x;
    int tc = tid & 15;       // col quad
    int tr = tid >> 4;       // row quad
    int lrow = tid >> 2;     // 0..63 staging row
    int lseg = (tid & 3) * 16;

    float acc[4][4];
#pragma unroll
    for (int i = 0; i < 4; i++)
#pragma unroll
        for (int j = 0; j < 4; j++) acc[i][j] = 0.f;

    int ar = row0 + lrow;
    for (int k0 = 0; k0 < F_IN; k0 += 64) {
#pragma unroll
        for (int q = 0; q < 4; q++) {
            float4 av = make_float4(0.f, 0.f, 0.f, 0.f);
            if (ar < N) av = *(const float4*)(x + (size_t)ar * F_IN + k0 + lseg + q * 4);
            *(float4*)&As[lrow][lseg + q * 4] = av;
            float4 bv = *(const float4*)(W1 + (size_t)(k0 + lrow) * F1 + lseg + q * 4);
            *(float4*)&Bs[lrow][lseg + q * 4] = bv;
        }
        __syncthreads();

#pragma unroll
        for (int kk = 0; kk < 64; kk += 4) {
            float a[4][4], b[4][4];
#pragma unroll
            for (int i = 0; i < 4; i++)
                *(float4*)&a[i][0] = *(const float4*)&As[tr * 4 + i][kk];
#pragma unroll
            for (int kx = 0; kx < 4; kx++)
                *(float4*)&b[kx][0] = *(const float4*)&Bs[kk + kx][tc * 4];
#pragma unroll
            for (int kx = 0; kx < 4; kx++)
#pragma unroll
                for (int i = 0; i < 4; i++)
#pragma unroll
                    for (int j = 0; j < 4; j++)
                        acc[i][j] = fmaf(a[i][kx], b[kx][j], acc[i][j]);
        }
        __syncthreads();
    }

    float4 ats = *(const float4*)(att_s + tc * 4);
    float4 atd = *(const float4*)(att_d + tc * 4);
#pragma unroll
    for (int i = 0; i < 4; i++) {
        int r = row0 + tr * 4 + i;
        if (r < N) {
            float4 o = make_float4(acc[i][0], acc[i][1], acc[i][2], acc[i][3]);
            *(float4*)(h1 + (size_t)r * F1 + tc * 4) = o;
        }
        float ps = acc[i][0] * ats.x + acc[i][1] * ats.y + acc[i][2] * ats.z + acc[i][3] * ats.w;
        float pd = acc[i][0] * atd.x + acc[i][1] * atd.y + acc[i][2] * atd.z + acc[i][3] * atd.w;
        ps += __shfl_xor(ps, 1);
        pd += __shfl_xor(pd, 1);
        if (r < N && (tc & 1) == 0) {
            a_s1[(size_t)r * 8 + (tc >> 1)] = ps;
            a_d1[(size_t)r * 8 + (tc >> 1)] = pd;
        }
    }
}

// ---------------- fused A: gemm1 (rows [0,rowSplit)) || edge decode + hist --
// Even blocks: gemm tile (blockIdx>>1). Odd blocks: edge chunk (blockIdx>>1)
// of nch chunks, 4-batched grid-stride for MLP.

__global__ __launch_bounds__(256) void k_fusedA(const float* __restrict__ x,
                                                const float* __restrict__ W1,
                                                const float* __restrict__ att_s,
                                                const float* __restrict__ att_d,
                                                float* __restrict__ h1,
                                                float* __restrict__ a_s1,
                                                float* __restrict__ a_d1, int N,
                                                const int* __restrict__ ei,
                                                const unsigned* __restrict__ mode,
                                                int* __restrict__ src32,
                                                int* __restrict__ dst32,
                                                unsigned* __restrict__ deg,
                                                int E, int ET, int nch) {
    __shared__ float As[64][68];
    __shared__ float Bs[64][68];
    unsigned b = blockIdx.x;
    if ((b & 1) == 0) {
        gemm1_tile(x, W1, att_s, att_d, h1, a_s1, a_d1, N, (int)(b >> 1) * 64, As, Bs);
        return;
    }
    // edge path
    const unsigned stride = (unsigned)nch * 256u;
    unsigned t = (b >> 1) * 256u + threadIdx.x;
    bool m64 = (*mode != 0u);
    const long long* e64 = (const long long*)ei;
    unsigned i = t;
    for (; i + 3u * stride < (unsigned)ET; i += 4u * stride) {
        unsigned i0 = i, i1 = i + stride, i2 = i + 2u * stride, i3 = i + 3u * stride;
        int s0, v0, s1, v1, s2, v2, s3, v3;
        if (m64) {
            s0 = (int)e64[i0]; s1 = (int)e64[i1]; s2 = (int)e64[i2]; s3 = (int)e64[i3];
            v0 = (i0 < (unsigned)E) ? (int)e64[E + i0] : (int)(i0 - E);
            v1 = (i1 < (unsigned)E) ? (int)e64[E + i1] : (int)(i1 - E);
            v2 = (i2 < (unsigned)E) ? (int)e64[E + i2] : (int)(i2 - E);
            v3 = (i3 < (unsigned)E) ? (int)e64[E + i3] : (int)(i3 - E);
        } else {
            s0 = ei[i0]; s1 = ei[i1]; s2 = ei[i2]; s3 = ei[i3];
            v0 = (i0 < (unsigned)E) ? ei[E + i0] : (int)(i0 - E);
            v1 = (i1 < (unsigned)E) ? ei[E + i1] : (int)(i1 - E);
            v2 = (i2 < (unsigned)E) ? ei[E + i2] : (int)(i2 - E);
            v3 = (i3 < (unsigned)E) ? ei[E + i3] : (int)(i3 - E);
        }
        if (i0 >= (unsigned)E) s0 = (int)(i0 - E);
        if (i1 >= (unsigned)E) s1 = (int)(i1 - E);
        if (i2 >= (unsigned)E) s2 = (int)(i2 - E);
        if (i3 >= (unsigned)E) s3 = (int)(i3 - E);
        s0 = s0 < 0 ? 0 : (s0 >= N ? N - 1 : s0);  v0 = v0 < 0 ? 0 : (v0 >= N ? N - 1 : v0);
        s1 = s1 < 0 ? 0 : (s1 >= N ? N - 1 : s1);  v1 = v1 < 0 ? 0 : (v1 >= N ? N - 1 : v1);
        s2 = s2 < 0 ? 0 : (s2 >= N ? N - 1 : s2);  v2 = v2 < 0 ? 0 : (v2 >= N ? N - 1 : v2);
        s3 = s3 < 0 ? 0 : (s3 >= N ? N - 1 : s3);  v3 = v3 < 0 ? 0 : (v3 >= N ? N - 1 : v3);
        src32[i0] = s0; dst32[i0] = v0;
        src32[i1] = s1; dst32[i1] = v1;
        src32[i2] = s2; dst32[i2] = v2;
        src32[i3] = s3; dst32[i3] = v3;
        atomicAdd(&deg[v0], 1u);
        atomicAdd(&deg[v1], 1u);
        atomicAdd(&deg[v2], 1u);
        atomicAdd(&deg[v3], 1u);
    }
    for (; i < (unsigned)ET; i += stride) {
        int s, v;
        if (i < (unsigned)E) {
            if (m64) { s = (int)e64[i]; v = (int)e64[E + i]; }
            else     { s = ei[i];       v = ei[E + i]; }
        } else {
            s = v = (int)(i - E);
        }
        s = s < 0 ? 0 : (s >= N ? N - 1 : s);
        v = v < 0 ? 0 : (v >= N ? N - 1 : v);
        src32[i] = s; dst32[i] = v;
        atomicAdd(&deg[v], 1u);
    }
}

// ---------------- fused B: gemm1 (rows [rowSplit,N)) || scatter ----------

__global__ __launch_bounds__(256) void k_fusedB(const float* __restrict__ x,
                                                const float* __restrict__ W1,
                                                const float* __restrict__ att_s,
                                                const float* __restrict__ att_d,
                                                float* __restrict__ h1,
                                                float* __restrict__ a_s1,
                                                float* __restrict__ a_d1, int N,
                                                int rowSplit,
                                                const int* __restrict__ src32,
                                                const int* __restrict__ dst32,
                                                unsigned* __restrict__ fill_ptr,
                                                unsigned* __restrict__ ssrc,
                                                int ET, int nch) {
    __shared__ float As[64][68];
    __shared__ float Bs[64][68];
    unsigned b = blockIdx.x;
    if (b & 1) {
        gemm1_tile(x, W1, att_s, att_d, h1, a_s1, a_d1, N,
                   rowSplit + (int)(b >> 1) * 64, As, Bs);
        return;
    }
    // scatter path
    const unsigned stride = (unsigned)nch * 256u;
    unsigned t = (b >> 1) * 256u + threadIdx.x;
    unsigned i = t;
    for (; i + 3u * stride < (unsigned)ET; i += 4u * stride) {
        unsigned i0 = i, i1 = i + stride, i2 = i + 2u * stride, i3 = i + 3u * stride;
        int v0 = dst32[i0], v1 = dst32[i1], v2 = dst32[i2], v3 = dst32[i3];
        int s0 = src32[i0], s1 = src32[i1], s2 = src32[i2], s3 = src32[i3];
        unsigned p0 = atomicAdd(&fill_ptr[v0], 1u);
        unsigned p1 = atomicAdd(&fill_ptr[v1], 1u);
        unsigned p2 = atomicAdd(&fill_ptr[v2], 1u);
        unsigned p3 = atomicAdd(&fill_ptr[v3], 1u);
        ssrc[p0] = (unsigned)s0;
        ssrc[p1] = (unsigned)s1;
        ssrc[p2] = (unsigned)s2;
        ssrc[p3] = (unsigned)s3;
    }
    for (; i < (unsigned)ET; i += stride) {
        int v = dst32[i], s = src32[i];
        unsigned p = atomicAdd(&fill_ptr[v], 1u);
        ssrc[p] = (unsigned)s;
    }
}

// ---------------- CSR prefix-sum kernels ----------------

__global__ __launch_bounds__(256) void k_tilesum(const unsigned* __restrict__ deg,
                                                 int N, unsigned* __restrict__ tileSum) {
    int tid = threadIdx.x;
    int v = blockIdx.x * 256 + tid;
    unsigned d = (v < N) ? deg[v] : 0u;
    for (int off = 1; off < 64; off <<= 1) d += __shfl_xor(d, off);
    __shared__ unsigned ps[4];
    int lane = tid & 63, wid = tid >> 6;
    if (lane == 0) ps[wid] = d;
    __syncthreads();
    if (tid == 0) tileSum[blockIdx.x] = ps[0] + ps[1] + ps[2] + ps[3];
}

__global__ __launch_bounds__(1024) void k_scan_tiles(const unsigned* __restrict__ tileSum,
                                                     int nt, unsigned* __restrict__ tileOfs) {
    __shared__ unsigned sbuf[1024];
    int t = threadIdx.x;
    unsigned val = (t < nt) ? tileSum[t] : 0u;
    sbuf[t] = val;
    __syncthreads();
    for (int off = 1; off < 1024; off <<= 1) {
        unsigned add = (t >= off) ? sbuf[t - off] : 0u;
        __syncthreads();
        sbuf[t] += add;
        __syncthreads();
    }
    if (t < nt) tileOfs[t] = sbuf[t] - val;  // exclusive
}

__global__ __launch_bounds__(256) void k_rowptr(const unsigned* __restrict__ deg,
                                                const unsigned* __restrict__ tileOfs,
                                                unsigned* __restrict__ row_ptr,
                                                unsigned* __restrict__ fill_ptr,
                                                int N, int ET) {
    __shared__ unsigned sbuf[256];
    int t = threadIdx.x;
    int v = blockIdx.x * 256 + t;
    unsigned d = (v < N) ? deg[v] : 0u;
    sbuf[t] = d;
    __syncthreads();
    for (int off = 1; off < 256; off <<= 1) {
        unsigned add = (t >= off) ? sbuf[t - off] : 0u;
        __syncthreads();
        sbuf[t] += add;
        __syncthreads();
    }
    if (v < N) {
        unsigned excl = tileOfs[blockIdx.x] + sbuf[t] - d;
        row_ptr[v] = excl;
        fill_ptr[v] = excl;
    }
    if (blockIdx.x == 0 && t == 0) row_ptr[N] = (unsigned)ET;
}

// ---------------- layer-1 aggregation: one wave per dst node ----------------
// Single-pass softmax, 4-deep unroll for MLP. lane = head*8 + channel.

__global__ __launch_bounds__(256) void k_agg1(const float* __restrict__ h1,
                                              const float* __restrict__ a_s1,
                                              const float* __restrict__ a_d1,
                                              const float* __restrict__ b1,
                                              const unsigned* __restrict__ row_ptr,
                                              const unsigned* __restrict__ ssrc,
                                              float* __restrict__ g, int N) {
    int wid = threadIdx.x >> 6, lane = threadIdx.x & 63;
    int v = blockIdx.x * 4 + wid;
    if (v >= N) return;
    unsigned base = row_ptr[v];
    unsigned deg = row_ptr[v + 1] - base;
    int h = lane >> 3;
    float adv = a_d1[(size_t)v * 8 + h];

    float denom = 0.f, acc = 0.f;
    unsigned j = 0;
    for (; j + 4 <= deg; j += 4) {
        unsigned s0 = ssrc[base + j + 0];
        unsigned s1 = ssrc[base + j + 1];
        unsigned s2 = ssrc[base + j + 2];
        unsigned s3 = ssrc[base + j + 3];
        float as0 = a_s1[(size_t)s0 * 8 + h];
        float as1 = a_s1[(size_t)s1 * 8 + h];
        float as2 = a_s1[(size_t)s2 * 8 + h];
        float as3 = a_s1[(size_t)s3 * 8 + h];
        float h0 = h1[(size_t)s0 * F1 + lane];
        float hv1 = h1[(size_t)s1 * F1 + lane];
        float hv2 = h1[(size_t)s2 * F1 + lane];
        float hv3 = h1[(size_t)s3 * F1 + lane];
        float e0 = as0 + adv; e0 = e0 > 0.f ? e0 : NEG_SLOPE * e0; float p0 = __expf(e0);
        float e1 = as1 + adv; e1 = e1 > 0.f ? e1 : NEG_SLOPE * e1; float p1 = __expf(e1);
        float e2 = as2 + adv; e2 = e2 > 0.f ? e2 : NEG_SLOPE * e2; float p2 = __expf(e2);
        float e3 = as3 + adv; e3 = e3 > 0.f ? e3 : NEG_SLOPE * e3; float p3 = __expf(e3);
        denom += (p0 + p1) + (p2 + p3);
        acc = fmaf(h0, p0, acc);
        acc = fmaf(hv1, p1, acc);
        acc = fmaf(hv2, p2, acc);
        acc = fmaf(hv3, p3, acc);
    }
    for (; j < deg; j++) {
        unsigned s = ssrc[base + j];
        float as = a_s1[(size_t)s * 8 + h];
        float hv = h1[(size_t)s * F1 + lane];
        float e = as + adv; e = e > 0.f ? e : NEG_SLOPE * e;
        float p = __expf(e);
        denom += p;
        acc = fmaf(hv, p, acc);
    }
    float t = acc * (1.0f / denom) + b1[lane];
    g[(size_t)v * F1 + lane] = t > 0.f ? t : (__expf(t) - 1.f);  // ELU
}

// ---------------- GEMM2 + attention dots layer 2 ----------------

__global__ __launch_bounds__(256) void k_gemm2(const float* __restrict__ g,
                                               const float* __restrict__ W2,
                                               const float* __restrict__ as2w,
                                               const float* __restrict__ ad2w,
                                               float* __restrict__ h2,
                                               float* __restrict__ a_s2,
                                               float* __restrict__ a_d2, int N) {
    __shared__ float W2s[F1][NCLS];
    int tid = threadIdx.x;
    for (int i = tid; i < F1 * NCLS; i += 256) ((float*)W2s)[i] = W2[i];
    __syncthreads();
    int lane = tid & 63, wid = tid >> 6;
    int n = blockIdx.x * 16 + wid * 4 + (lane >> 4);
    int c = lane & 15;
    if (n >= N) return;
    float acc = 0.f;
#pragma unroll
    for (int k4 = 0; k4 < 16; k4++) {
        float4 gv = *(const float4*)(g + (size_t)n * F1 + k4 * 4);
        acc = fmaf(gv.x, W2s[k4 * 4 + 0][c], acc);
        acc = fmaf(gv.y, W2s[k4 * 4 + 1][c], acc);
        acc = fmaf(gv.z, W2s[k4 * 4 + 2][c], acc);
        acc = fmaf(gv.w, W2s[k4 * 4 + 3][c], acc);
    }
    h2[(size_t)n * NCLS + c] = acc;
    float s = acc * as2w[c];
    float d = acc * ad2w[c];
    s += __shfl_xor(s, 1); s += __shfl_xor(s, 2); s += __shfl_xor(s, 4); s += __shfl_xor(s, 8);
    d += __shfl_xor(d, 1); d += __shfl_xor(d, 2); d += __shfl_xor(d, 4); d += __shfl_xor(d, 8);
    if (c == 0) { a_s2[n] = s; a_d2[n] = d; }
}

// ---------------- layer-2 aggregation (single-pass) -> fp32 output ----------

__global__ __launch_bounds__(256) void k_agg2(const float* __restrict__ h2,
                                              const float* __restrict__ a_s2,
                                              const float* __restrict__ a_d2,
                                              const float* __restrict__ b2,
                                              const unsigned* __restrict__ row_ptr,
                                              const unsigned* __restrict__ ssrc,
                                              float* __restrict__ out, int N) {
    int wid = threadIdx.x >> 6, lane = threadIdx.x & 63;
    int v = blockIdx.x * 4 + wid;
    if (v >= N) return;
    unsigned base = row_ptr[v];
    unsigned deg = row_ptr[v + 1] - base;
    float adv = a_d2[v];
    int sub = lane >> 4, c = lane & 15;

    float denom = 0.f, acc = 0.f;
    for (unsigned j = sub; j < deg; j += 4) {
        unsigned s = ssrc[base + j];
        float as = a_s2[s];
        float hv = h2[(size_t)s * NCLS + c];
        float e = as + adv; e = e > 0.f ? e : NEG_SLOPE * e;
        float p = __expf(e);
        denom += p;
        acc = fmaf(hv, p, acc);
    }
    acc += __shfl_xor(acc, 16);
    acc += __shfl_xor(acc, 32);
    denom += __shfl_xor(denom, 16);
    denom += __shfl_xor(denom, 32);
    if (lane < 16) {
        out[(size_t)v * NCLS + c] = acc * (1.0f / denom) + b2[c];
    }
}

// ---------------- launch ----------------

static inline size_t algn(size_t x) { return (x + 255) & ~(size_t)255; }

extern "C" void kernel_launch(void* const* d_in, const int* in_sizes, int n_in,
                              void* d_out, int out_size, void* d_ws, size_t ws_size,
                              hipStream_t stream) {
    const float* x   = (const float*)d_in[0];
    const int* ei    = (const int*)d_in[1];
    const float* W1  = (const float*)d_in[2];
    const float* as1 = (const float*)d_in[3];
    const float* ad1 = (const float*)d_in[4];
    const float* b1  = (const float*)d_in[5];
    const float* W2  = (const float*)d_in[6];
    const float* as2 = (const float*)d_in[7];
    const float* ad2 = (const float*)d_in[8];
    const float* b2  = (const float*)d_in[9];

    const int N = in_sizes[0] / F_IN;
    const int E = in_sizes[1] / 2;
    const int ET = E + N;
    const int nt = (N + 255) / 256;   // scan tiles (<= 1024)

    // row split for the two gemm halves (multiple of 64)
    const int GA_T = ((N / 2) + 63) / 64;       // tiles in half A
    const int rowSplit = GA_T * 64;
    const int GB_T = (N - rowSplit + 63) / 64;  // tiles in half B

    char* p = (char*)d_ws;
    float* h1   = (float*)p;      p += algn((size_t)N * F1 * 4);
    float* g    = (float*)p;      p += algn((size_t)N * F1 * 4);
    float* a_s1 = (float*)p;      p += algn((size_t)N * 8 * 4);
    float* a_d1 = (float*)p;      p += algn((size_t)N * 8 * 4);
    float* h2   = (float*)p;      p += algn((size_t)N * NCLS * 4);
    float* a_s2 = (float*)p;      p += algn((size_t)N * 4);
    float* a_d2 = (float*)p;      p += algn((size_t)N * 4);
    unsigned* deg     = (unsigned*)p;  p += algn((size_t)N * 4);
    unsigned* fill    = (unsigned*)p;  p += algn((size_t)N * 4);
    unsigned* row_ptr = (unsigned*)p;  p += algn((size_t)(N + 1) * 4);
    unsigned* tileSum = (unsigned*)p;  p += algn((size_t)1024 * 4);
    unsigned* tileOfs = (unsigned*)p;  p += algn((size_t)1024 * 4);
    unsigned* mode    = (unsigned*)p;  p += algn(256);
    int* src32 = (int*)p;              p += algn((size_t)ET * 4);
    int* dst32 = (int*)p;              p += algn((size_t)ET * 4);
    unsigned* ssrc = (unsigned*)p;     p += algn((size_t)ET * 4);

    hipMemsetAsync(deg, 0, (size_t)N * 4, stream);

    dim3 b256(256);
    k_detect<<<dim3(1), dim3(64), 0, stream>>>(ei, E, mode);

    // A: gemm rows [0,rowSplit) interleaved with edge decode + degree hist
    k_fusedA<<<dim3(2 * GA_T), b256, 0, stream>>>(x, W1, as1, ad1, h1, a_s1, a_d1, N,
                                                  ei, mode, src32, dst32, deg, E, ET, GA_T);

    k_tilesum<<<dim3(nt), b256, 0, stream>>>(deg, N, tileSum);
    k_scan_tiles<<<dim3(1), dim3(1024), 0, stream>>>(tileSum, nt, tileOfs);
    k_rowptr<<<dim3(nt), b256, 0, stream>>>(deg, tileOfs, row_ptr, fill, N, ET);

    // B: gemm rows [rowSplit,N) interleaved with scatter
    k_fusedB<<<dim3(2 * GB_T), b256, 0, stream>>>(x, W1, as1, ad1, h1, a_s1, a_d1, N,
                                                  rowSplit, src32, dst32, fill, ssrc, ET, GB_T);

    k_agg1<<<dim3((N + 3) / 4), b256, 0, stream>>>(h1, a_s1, a_d1, b1, row_ptr, ssrc, g, N);
    k_gemm2<<<dim3((N + 15) / 16), b256, 0, stream>>>(g, W2, as2, ad2, h2, a_s2, a_d2, N);
    k_agg2<<<dim3((N + 3) / 4), b256, 0, stream>>>(h2, a_s2, a_d2, b2, row_ptr, ssrc,
                                                   (float*)d_out, N);
}

// Round 5
// 768.480 us; speedup vs baseline: 1.6618x; 1.0484x over previous
//
#include <hip/hip_runtime.h>

// Problem constants (from reference setup_inputs)
#define F_IN 512
#define F1 64          // HEADS*HID = 8*8
#define NCLS 16
#define NEG_SLOPE 0.2f

typedef __attribute__((ext_vector_type(8))) short short8;
typedef __attribute__((ext_vector_type(4))) float f32x4;

__device__ __forceinline__ unsigned short f2bf(float f) {
    unsigned u = __float_as_uint(f);
    return (unsigned short)((u + 0x7fffu + ((u >> 16) & 1u)) >> 16);
}
__device__ __forceinline__ float bf2f(unsigned short u) {
    return __uint_as_float(((unsigned)u) << 16);
}

// ---------------- edge decode (int32 vs int64 robust) ----------------

__global__ __launch_bounds__(64) void k_detect(const int* __restrict__ ei, int E,
                                               unsigned* __restrict__ mode) {
    int t = threadIdx.x;
    unsigned nz = 0;
    int lim = (E > 256) ? 256 : E;
    for (int k = t; k < lim; k += 64) nz |= (unsigned)ei[2 * k + 1];
    for (int off = 1; off < 64; off <<= 1) nz |= __shfl_xor(nz, off);
    if (t == 0) *mode = (nz == 0) ? 1u : 0u;   // 1 = int64 layout
}

// ---------------- GEMM1 MFMA tile (bf16 in, fp32 acc) ----------------
// 64 rows x 64 cols per block, K=512 in chunks of 32. 4 waves; wave w owns
// rows w*16..w*16+15 as 4 MFMA 16x16 col-tiles. Fragment layouts (verified
// per guide §3): A[m=lane&15][k=quad*8+j]; B[k=quad*8+j][n=lane&15];
// C/D col=lane&15, row=quad*4+reg.
// Epilogue: h1 stored bf16; per-head att dots from fp32 accumulators.

__device__ __forceinline__ void gemm1_tile(const float* __restrict__ x,
                                           const float* __restrict__ W1,
                                           const float* __restrict__ att_s,
                                           const float* __restrict__ att_d,
                                           unsigned short* __restrict__ h1b,
                                           float* __restrict__ a_s1,
                                           float* __restrict__ a_d1,
                                           int N, int row0,
                                           unsigned short (*Abuf)[40],
                                           unsigned short (*BbufT)[40]) {
    const int tid = threadIdx.x;
    const int w = tid >> 6, lane = tid & 63;
    const int quad = lane >> 4, r16 = lane & 15;

    f32x4 acc[4];
#pragma unroll
    for (int t = 0; t < 4; t++) acc[t] = (f32x4){0.f, 0.f, 0.f, 0.f};

    // staging indices
    const int a_row = tid >> 2;             // 0..63
    const int a_seg = (tid & 3) * 8;        // 0,8,16,24
    const int b_col = tid & 63;             // 0..63
    const int b_kq  = tid >> 6;             // 0..3 (wave id)
    const int ar = row0 + a_row;

    for (int k0 = 0; k0 < F_IN; k0 += 32) {
        // stage A: x[row0..+63][k0..+31] -> bf16
        {
            float4 v0 = make_float4(0.f, 0.f, 0.f, 0.f), v1 = v0;
            if (ar < N) {
                const float* xp = x + (size_t)ar * F_IN + k0 + a_seg;
                v0 = *(const float4*)xp;
                v1 = *(const float4*)(xp + 4);
            }
            short8 cv;
            cv[0] = (short)f2bf(v0.x); cv[1] = (short)f2bf(v0.y);
            cv[2] = (short)f2bf(v0.z); cv[3] = (short)f2bf(v0.w);
            cv[4] = (short)f2bf(v1.x); cv[5] = (short)f2bf(v1.y);
            cv[6] = (short)f2bf(v1.z); cv[7] = (short)f2bf(v1.w);
            *(short8*)&Abuf[a_row][a_seg] = cv;
        }
        // stage B transposed: W1[k0+kq*8+j][col] -> BbufT[col][kq*8+j]
        {
            const float* wp = W1 + (size_t)(k0 + b_kq * 8) * F1 + b_col;
            short8 cv;
#pragma unroll
            for (int j = 0; j < 8; j++)
                cv[j] = (short)f2bf(wp[(size_t)j * F1]);
            *(short8*)&BbufT[b_col][b_kq * 8] = cv;
        }
        __syncthreads();

        short8 af = *(const short8*)&Abuf[w * 16 + r16][quad * 8];
#pragma unroll
        for (int t = 0; t < 4; t++) {
            short8 bf = *(const short8*)&BbufT[t * 16 + r16][quad * 8];
            acc[t] = __builtin_amdgcn_mfma_f32_16x16x32_bf16(af, bf, acc[t], 0, 0, 0);
        }
        __syncthreads();
    }

    // epilogue
    float ats[4], atd[4];
#pragma unroll
    for (int t = 0; t < 4; t++) {
        ats[t] = att_s[t * 16 + r16];
        atd[t] = att_d[t * 16 + r16];
    }
#pragma unroll
    for (int r = 0; r < 4; r++) {
        int grow = row0 + w * 16 + quad * 4 + r;
        bool ok = grow < N;
        float ps[4], pd[4];
#pragma unroll
        for (int t = 0; t < 4; t++) {
            float vv = acc[t][r];
            if (ok) h1b[(size_t)grow * F1 + t * 16 + r16] = f2bf(vv);
            ps[t] = vv * ats[t];
            pd[t] = vv * atd[t];
        }
#pragma unroll
        for (int t = 0; t < 4; t++) {
            ps[t] += __shfl_xor(ps[t], 1); pd[t] += __shfl_xor(pd[t], 1);
            ps[t] += __shfl_xor(ps[t], 2); pd[t] += __shfl_xor(pd[t], 2);
            ps[t] += __shfl_xor(ps[t], 4); pd[t] += __shfl_xor(pd[t], 4);
        }
        if (ok && (r16 & 7) == 0) {
            int hh0 = r16 >> 3;   // 0 or 1
#pragma unroll
            for (int t = 0; t < 4; t++) {
                a_s1[(size_t)grow * 8 + t * 2 + hh0] = ps[t];
                a_d1[(size_t)grow * 8 + t * 2 + hh0] = pd[t];
            }
        }
    }
}

// ---------------- fused A: gemm1 (rows [0,rowSplit)) || edge decode + hist --

__global__ __launch_bounds__(256) void k_fusedA(const float* __restrict__ x,
                                                const float* __restrict__ W1,
                                                const float* __restrict__ att_s,
                                                const float* __restrict__ att_d,
                                                unsigned short* __restrict__ h1b,
                                                float* __restrict__ a_s1,
                                                float* __restrict__ a_d1, int N,
                                                const int* __restrict__ ei,
                                                const unsigned* __restrict__ mode,
                                                int* __restrict__ src32,
                                                int* __restrict__ dst32,
                                                unsigned* __restrict__ deg,
                                                int E, int ET, int nch) {
    __shared__ unsigned short Abuf[64][40];
    __shared__ unsigned short BbufT[64][40];
    unsigned b = blockIdx.x;
    if ((b & 1) == 0) {
        gemm1_tile(x, W1, att_s, att_d, h1b, a_s1, a_d1, N, (int)(b >> 1) * 64,
                   Abuf, BbufT);
        return;
    }
    // edge path: decode + clamp + degree histogram, 4-batched
    const unsigned stride = (unsigned)nch * 256u;
    unsigned t = (b >> 1) * 256u + threadIdx.x;
    bool m64 = (*mode != 0u);
    const long long* e64 = (const long long*)ei;
    unsigned i = t;
    for (; i + 3u * stride < (unsigned)ET; i += 4u * stride) {
        unsigned i0 = i, i1 = i + stride, i2 = i + 2u * stride, i3 = i + 3u * stride;
        int s0, v0, s1, v1, s2, v2, s3, v3;
        if (m64) {
            s0 = (int)e64[i0]; s1 = (int)e64[i1]; s2 = (int)e64[i2]; s3 = (int)e64[i3];
            v0 = (i0 < (unsigned)E) ? (int)e64[E + i0] : (int)(i0 - E);
            v1 = (i1 < (unsigned)E) ? (int)e64[E + i1] : (int)(i1 - E);
            v2 = (i2 < (unsigned)E) ? (int)e64[E + i2] : (int)(i2 - E);
            v3 = (i3 < (unsigned)E) ? (int)e64[E + i3] : (int)(i3 - E);
        } else {
            s0 = ei[i0]; s1 = ei[i1]; s2 = ei[i2]; s3 = ei[i3];
            v0 = (i0 < (unsigned)E) ? ei[E + i0] : (int)(i0 - E);
            v1 = (i1 < (unsigned)E) ? ei[E + i1] : (int)(i1 - E);
            v2 = (i2 < (unsigned)E) ? ei[E + i2] : (int)(i2 - E);
            v3 = (i3 < (unsigned)E) ? ei[E + i3] : (int)(i3 - E);
        }
        if (i0 >= (unsigned)E) s0 = (int)(i0 - E);
        if (i1 >= (unsigned)E) s1 = (int)(i1 - E);
        if (i2 >= (unsigned)E) s2 = (int)(i2 - E);
        if (i3 >= (unsigned)E) s3 = (int)(i3 - E);
        s0 = s0 < 0 ? 0 : (s0 >= N ? N - 1 : s0);  v0 = v0 < 0 ? 0 : (v0 >= N ? N - 1 : v0);
        s1 = s1 < 0 ? 0 : (s1 >= N ? N - 1 : s1);  v1 = v1 < 0 ? 0 : (v1 >= N ? N - 1 : v1);
        s2 = s2 < 0 ? 0 : (s2 >= N ? N - 1 : s2);  v2 = v2 < 0 ? 0 : (v2 >= N ? N - 1 : v2);
        s3 = s3 < 0 ? 0 : (s3 >= N ? N - 1 : s3);  v3 = v3 < 0 ? 0 : (v3 >= N ? N - 1 : v3);
        src32[i0] = s0; dst32[i0] = v0;
        src32[i1] = s1; dst32[i1] = v1;
        src32[i2] = s2; dst32[i2] = v2;
        src32[i3] = s3; dst32[i3] = v3;
        atomicAdd(&deg[v0], 1u);
        atomicAdd(&deg[v1], 1u);
        atomicAdd(&deg[v2], 1u);
        atomicAdd(&deg[v3], 1u);
    }
    for (; i < (unsigned)ET; i += stride) {
        int s, v;
        if (i < (unsigned)E) {
            if (m64) { s = (int)e64[i]; v = (int)e64[E + i]; }
            else     { s = ei[i];       v = ei[E + i]; }
        } else {
            s = v = (int)(i - E);
        }
        s = s < 0 ? 0 : (s >= N ? N - 1 : s);
        v = v < 0 ? 0 : (v >= N ? N - 1 : v);
        src32[i] = s; dst32[i] = v;
        atomicAdd(&deg[v], 1u);
    }
}

// ---------------- fused B: gemm1 (rows [rowSplit,N)) || scatter ----------

__global__ __launch_bounds__(256) void k_fusedB(const float* __restrict__ x,
                                                const float* __restrict__ W1,
                                                const float* __restrict__ att_s,
                                                const float* __restrict__ att_d,
                                                unsigned short* __restrict__ h1b,
                                                float* __restrict__ a_s1,
                                                float* __restrict__ a_d1, int N,
                                                int rowSplit,
                                                const int* __restrict__ src32,
                                                const int* __restrict__ dst32,
                                                unsigned* __restrict__ fill_ptr,
                                                unsigned* __restrict__ ssrc,
                                                int ET, int nch) {
    __shared__ unsigned short Abuf[64][40];
    __shared__ unsigned short BbufT[64][40];
    unsigned b = blockIdx.x;
    if (b & 1) {
        gemm1_tile(x, W1, att_s, att_d, h1b, a_s1, a_d1, N,
                   rowSplit + (int)(b >> 1) * 64, Abuf, BbufT);
        return;
    }
    // scatter path, 4-batched
    const unsigned stride = (unsigned)nch * 256u;
    unsigned t = (b >> 1) * 256u + threadIdx.x;
    unsigned i = t;
    for (; i + 3u * stride < (unsigned)ET; i += 4u * stride) {
        unsigned i0 = i, i1 = i + stride, i2 = i + 2u * stride, i3 = i + 3u * stride;
        int v0 = dst32[i0], v1 = dst32[i1], v2 = dst32[i2], v3 = dst32[i3];
        int s0 = src32[i0], s1 = src32[i1], s2 = src32[i2], s3 = src32[i3];
        unsigned p0 = atomicAdd(&fill_ptr[v0], 1u);
        unsigned p1 = atomicAdd(&fill_ptr[v1], 1u);
        unsigned p2 = atomicAdd(&fill_ptr[v2], 1u);
        unsigned p3 = atomicAdd(&fill_ptr[v3], 1u);
        ssrc[p0] = (unsigned)s0;
        ssrc[p1] = (unsigned)s1;
        ssrc[p2] = (unsigned)s2;
        ssrc[p3] = (unsigned)s3;
    }
    for (; i < (unsigned)ET; i += stride) {
        int v = dst32[i], s = src32[i];
        unsigned p = atomicAdd(&fill_ptr[v], 1u);
        ssrc[p] = (unsigned)s;
    }
}

// ---------------- CSR prefix-sum kernels ----------------

__global__ __launch_bounds__(256) void k_tilesum(const unsigned* __restrict__ deg,
                                                 int N, unsigned* __restrict__ tileSum) {
    int tid = threadIdx.x;
    int v = blockIdx.x * 256 + tid;
    unsigned d = (v < N) ? deg[v] : 0u;
    for (int off = 1; off < 64; off <<= 1) d += __shfl_xor(d, off);
    __shared__ unsigned ps[4];
    int lane = tid & 63, wid = tid >> 6;
    if (lane == 0) ps[wid] = d;
    __syncthreads();
    if (tid == 0) tileSum[blockIdx.x] = ps[0] + ps[1] + ps[2] + ps[3];
}

__global__ __launch_bounds__(1024) void k_scan_tiles(const unsigned* __restrict__ tileSum,
                                                     int nt, unsigned* __restrict__ tileOfs) {
    __shared__ unsigned sbuf[1024];
    int t = threadIdx.x;
    unsigned val = (t < nt) ? tileSum[t] : 0u;
    sbuf[t] = val;
    __syncthreads();
    for (int off = 1; off < 1024; off <<= 1) {
        unsigned add = (t >= off) ? sbuf[t - off] : 0u;
        __syncthreads();
        sbuf[t] += add;
        __syncthreads();
    }
    if (t < nt) tileOfs[t] = sbuf[t] - val;  // exclusive
}

__global__ __launch_bounds__(256) void k_rowptr(const unsigned* __restrict__ deg,
                                                const unsigned* __restrict__ tileOfs,
                                                unsigned* __restrict__ row_ptr,
                                                unsigned* __restrict__ fill_ptr,
                                                int N, int ET) {
    __shared__ unsigned sbuf[256];
    int t = threadIdx.x;
    int v = blockIdx.x * 256 + t;
    unsigned d = (v < N) ? deg[v] : 0u;
    sbuf[t] = d;
    __syncthreads();
    for (int off = 1; off < 256; off <<= 1) {
        unsigned add = (t >= off) ? sbuf[t - off] : 0u;
        __syncthreads();
        sbuf[t] += add;
        __syncthreads();
    }
    if (v < N) {
        unsigned excl = tileOfs[blockIdx.x] + sbuf[t] - d;
        row_ptr[v] = excl;
        fill_ptr[v] = excl;
    }
    if (blockIdx.x == 0 && t == 0) row_ptr[N] = (unsigned)ET;
}

// ---------------- layer-1 aggregation: one wave per dst node ----------------
// Single-pass softmax; h1 gathered as bf16 (128B/edge/wave). lane = h*8+c.

__global__ __launch_bounds__(256) void k_agg1(const unsigned short* __restrict__ h1b,
                                              const float* __restrict__ a_s1,
                                              const float* __restrict__ a_d1,
                                              const float* __restrict__ b1,
                                              const unsigned* __restrict__ row_ptr,
                                              const unsigned* __restrict__ ssrc,
                                              float* __restrict__ g, int N) {
    int wid = threadIdx.x >> 6, lane = threadIdx.x & 63;
    int v = blockIdx.x * 4 + wid;
    if (v >= N) return;
    unsigned base = row_ptr[v];
    unsigned deg = row_ptr[v + 1] - base;
    int h = lane >> 3;
    float adv = a_d1[(size_t)v * 8 + h];

    float denom = 0.f, acc = 0.f;
    unsigned j = 0;
    for (; j + 4 <= deg; j += 4) {
        unsigned s0 = ssrc[base + j + 0];
        unsigned s1 = ssrc[base + j + 1];
        unsigned s2 = ssrc[base + j + 2];
        unsigned s3 = ssrc[base + j + 3];
        float as0 = a_s1[(size_t)s0 * 8 + h];
        float as1 = a_s1[(size_t)s1 * 8 + h];
        float as2 = a_s1[(size_t)s2 * 8 + h];
        float as3 = a_s1[(size_t)s3 * 8 + h];
        float h0 = bf2f(h1b[(size_t)s0 * F1 + lane]);
        float hv1 = bf2f(h1b[(size_t)s1 * F1 + lane]);
        float hv2 = bf2f(h1b[(size_t)s2 * F1 + lane]);
        float hv3 = bf2f(h1b[(size_t)s3 * F1 + lane]);
        float e0 = as0 + adv; e0 = e0 > 0.f ? e0 : NEG_SLOPE * e0; float p0 = __expf(e0);
        float e1 = as1 + adv; e1 = e1 > 0.f ? e1 : NEG_SLOPE * e1; float p1 = __expf(e1);
        float e2 = as2 + adv; e2 = e2 > 0.f ? e2 : NEG_SLOPE * e2; float p2 = __expf(e2);
        float e3 = as3 + adv; e3 = e3 > 0.f ? e3 : NEG_SLOPE * e3; float p3 = __expf(e3);
        denom += (p0 + p1) + (p2 + p3);
        acc = fmaf(h0, p0, acc);
        acc = fmaf(hv1, p1, acc);
        acc = fmaf(hv2, p2, acc);
        acc = fmaf(hv3, p3, acc);
    }
    for (; j < deg; j++) {
        unsigned s = ssrc[base + j];
        float as = a_s1[(size_t)s * 8 + h];
        float hv = bf2f(h1b[(size_t)s * F1 + lane]);
        float e = as + adv; e = e > 0.f ? e : NEG_SLOPE * e;
        float p = __expf(e);
        denom += p;
        acc = fmaf(hv, p, acc);
    }
    float t = acc * (1.0f / denom) + b1[lane];
    g[(size_t)v * F1 + lane] = t > 0.f ? t : (__expf(t) - 1.f);  // ELU
}

// ---------------- GEMM2 + attention dots layer 2 ----------------

__global__ __launch_bounds__(256) void k_gemm2(const float* __restrict__ g,
                                               const float* __restrict__ W2,
                                               const float* __restrict__ as2w,
                                               const float* __restrict__ ad2w,
                                               float* __restrict__ h2,
                                               float* __restrict__ a_s2,
                                               float* __restrict__ a_d2, int N) {
    __shared__ float W2s[F1][NCLS];
    int tid = threadIdx.x;
    for (int i = tid; i < F1 * NCLS; i += 256) ((float*)W2s)[i] = W2[i];
    __syncthreads();
    int lane = tid & 63, wid = tid >> 6;
    int n = blockIdx.x * 16 + wid * 4 + (lane >> 4);
    int c = lane & 15;
    if (n >= N) return;
    float acc = 0.f;
#pragma unroll
    for (int k4 = 0; k4 < 16; k4++) {
        float4 gv = *(const float4*)(g + (size_t)n * F1 + k4 * 4);
        acc = fmaf(gv.x, W2s[k4 * 4 + 0][c], acc);
        acc = fmaf(gv.y, W2s[k4 * 4 + 1][c], acc);
        acc = fmaf(gv.z, W2s[k4 * 4 + 2][c], acc);
        acc = fmaf(gv.w, W2s[k4 * 4 + 3][c], acc);
    }
    h2[(size_t)n * NCLS + c] = acc;
    float s = acc * as2w[c];
    float d = acc * ad2w[c];
    s += __shfl_xor(s, 1); s += __shfl_xor(s, 2); s += __shfl_xor(s, 4); s += __shfl_xor(s, 8);
    d += __shfl_xor(d, 1); d += __shfl_xor(d, 2); d += __shfl_xor(d, 4); d += __shfl_xor(d, 8);
    if (c == 0) { a_s2[n] = s; a_d2[n] = d; }
}

// ---------------- layer-2 aggregation (single-pass) -> fp32 output ----------

__global__ __launch_bounds__(256) void k_agg2(const float* __restrict__ h2,
                                              const float* __restrict__ a_s2,
                                              const float* __restrict__ a_d2,
                                              const float* __restrict__ b2,
                                              const unsigned* __restrict__ row_ptr,
                                              const unsigned* __restrict__ ssrc,
                                              float* __restrict__ out, int N) {
    int wid = threadIdx.x >> 6, lane = threadIdx.x & 63;
    int v = blockIdx.x * 4 + wid;
    if (v >= N) return;
    unsigned base = row_ptr[v];
    unsigned deg = row_ptr[v + 1] - base;
    float adv = a_d2[v];
    int sub = lane >> 4, c = lane & 15;

    float denom = 0.f, acc = 0.f;
    for (unsigned j = sub; j < deg; j += 4) {
        unsigned s = ssrc[base + j];
        float as = a_s2[s];
        float hv = h2[(size_t)s * NCLS + c];
        float e = as + adv; e = e > 0.f ? e : NEG_SLOPE * e;
        float p = __expf(e);
        denom += p;
        acc = fmaf(hv, p, acc);
    }
    acc += __shfl_xor(acc, 16);
    acc += __shfl_xor(acc, 32);
    denom += __shfl_xor(denom, 16);
    denom += __shfl_xor(denom, 32);
    if (lane < 16) {
        out[(size_t)v * NCLS + c] = acc * (1.0f / denom) + b2[c];
    }
}

// ---------------- launch ----------------

static inline size_t algn(size_t x) { return (x + 255) & ~(size_t)255; }

extern "C" void kernel_launch(void* const* d_in, const int* in_sizes, int n_in,
                              void* d_out, int out_size, void* d_ws, size_t ws_size,
                              hipStream_t stream) {
    const float* x   = (const float*)d_in[0];
    const int* ei    = (const int*)d_in[1];
    const float* W1  = (const float*)d_in[2];
    const float* as1 = (const float*)d_in[3];
    const float* ad1 = (const float*)d_in[4];
    const float* b1  = (const float*)d_in[5];
    const float* W2  = (const float*)d_in[6];
    const float* as2 = (const float*)d_in[7];
    const float* ad2 = (const float*)d_in[8];
    const float* b2  = (const float*)d_in[9];

    const int N = in_sizes[0] / F_IN;
    const int E = in_sizes[1] / 2;
    const int ET = E + N;
    const int nt = (N + 255) / 256;   // scan tiles (<= 1024)

    const int GA_T = ((N / 2) + 63) / 64;       // gemm tiles in half A
    const int rowSplit = GA_T * 64;
    const int GB_T = (N - rowSplit + 63) / 64;  // gemm tiles in half B

    char* p = (char*)d_ws;
    unsigned short* h1b = (unsigned short*)p;  p += algn((size_t)N * F1 * 2);
    float* g    = (float*)p;      p += algn((size_t)N * F1 * 4);
    float* a_s1 = (float*)p;      p += algn((size_t)N * 8 * 4);
    float* a_d1 = (float*)p;      p += algn((size_t)N * 8 * 4);
    float* h2   = (float*)p;      p += algn((size_t)N * NCLS * 4);
    float* a_s2 = (float*)p;      p += algn((size_t)N * 4);
    float* a_d2 = (float*)p;      p += algn((size_t)N * 4);
    unsigned* deg     = (unsigned*)p;  p += algn((size_t)N * 4);
    unsigned* fill    = (unsigned*)p;  p += algn((size_t)N * 4);
    unsigned* row_ptr = (unsigned*)p;  p += algn((size_t)(N + 1) * 4);
    unsigned* tileSum = (unsigned*)p;  p += algn((size_t)1024 * 4);
    unsigned* tileOfs = (unsigned*)p;  p += algn((size_t)1024 * 4);
    unsigned* mode    = (unsigned*)p;  p += algn(256);
    int* src32 = (int*)p;              p += algn((size_t)ET * 4);
    int* dst32 = (int*)p;              p += algn((size_t)ET * 4);
    unsigned* ssrc = (unsigned*)p;     p += algn((size_t)ET * 4);

    hipMemsetAsync(deg, 0, (size_t)N * 4, stream);

    dim3 b256(256);
    k_detect<<<dim3(1), dim3(64), 0, stream>>>(ei, E, mode);

    // A: gemm rows [0,rowSplit) interleaved with edge decode + degree hist
    k_fusedA<<<dim3(2 * GA_T), b256, 0, stream>>>(x, W1, as1, ad1, h1b, a_s1, a_d1, N,
                                                  ei, mode, src32, dst32, deg, E, ET, GA_T);

    k_tilesum<<<dim3(nt), b256, 0, stream>>>(deg, N, tileSum);
    k_scan_tiles<<<dim3(1), dim3(1024), 0, stream>>>(tileSum, nt, tileOfs);
    k_rowptr<<<dim3(nt), b256, 0, stream>>>(deg, tileOfs, row_ptr, fill, N, ET);

    // B: gemm rows [rowSplit,N) interleaved with scatter
    k_fusedB<<<dim3(2 * GB_T), b256, 0, stream>>>(x, W1, as1, ad1, h1b, a_s1, a_d1, N,
                                                  rowSplit, src32, dst32, fill, ssrc, ET, GB_T);

    k_agg1<<<dim3((N + 3) / 4), b256, 0, stream>>>(h1b, a_s1, a_d1, b1, row_ptr, ssrc, g, N);
    k_gemm2<<<dim3((N + 15) / 16), b256, 0, stream>>>(g, W2, as2, ad2, h2, a_s2, a_d2, N);
    k_agg2<<<dim3((N + 3) / 4), b256, 0, stream>>>(h2, a_s2, a_d2, b2, row_ptr, ssrc,
                                                   (float*)d_out, N);
}